// Round 6
// baseline (49.704 us; speedup 1.0000x reference)
//
#include <hip/hip_runtime.h>
#include <math.h>

// Problem constants (setup_inputs: L=8, B=2, N=2048)
constexpr int L = 8;
constexpr int B = 2;
constexpr int N = 2048;
constexpr int LB = L * B;            // 16
constexpr int ITEMS = LB * N;        // 32768 feature rows per side
constexpr int KF = 32;               // padded feature dim (28 used + residual)

constexpr float D_CLAMP2 = 100.0f;   // clamp on squared distance
constexpr float FAPE_EPS = 1e-4f;
constexpr float Z_CONST  = 10.0f;
constexpr float TEPS     = 1e-8f;

constexpr int THREADS = 256;
constexpr int NIT     = N / 64;              // 32 i-tiles per (l,b)
constexpr int JSPLIT  = 2;                   // j split per (l,b)
constexpr int JHALF   = N / JSPLIT;          // 1024
constexpr int NPASS   = JHALF / 128;         // 8
constexpr int FAPE_BLOCKS = LB * NIT * JSPLIT;   // 1024 (64 blocks per lb)

constexpr int PREP_THREADS = 64;
constexpr int PREP_BLOCKS  = ITEMS / PREP_THREADS;  // 512 (32 blocks per lb)

typedef __attribute__((ext_vector_type(8))) short bf16x8;
typedef __attribute__((ext_vector_type(4))) float f32x4;

__device__ __forceinline__ float fast_sqrtf(float x) {
    return __builtin_amdgcn_sqrtf(x);
}
__device__ __forceinline__ unsigned short f2bf(float x) {  // RNE f32->bf16
    unsigned u = __float_as_uint(x);
    u += 0x7fffu + ((u >> 16) & 1u);
    return (unsigned short)(u >> 16);
}
__device__ __forceinline__ float bf2f(unsigned short h) {
    return __uint_as_float((unsigned)h << 16);
}

__device__ __forceinline__ float wave_reduce_sum(float v) {
    #pragma unroll
    for (int off = 32; off > 0; off >>= 1)
        v += __shfl_down(v, off, 64);
    return v;            // valid in lane 0
}

__device__ __forceinline__ float block_reduce_sum(float v) {
    __shared__ float s[4];
    v = wave_reduce_sum(v);
    int lane = threadIdx.x & 63;
    int w    = threadIdx.x >> 6;
    __syncthreads();              // protect s[] from a previous call
    if (lane == 0) s[w] = v;
    __syncthreads();
    return s[0] + s[1] + s[2] + s[3];   // fixed order -> deterministic
}

// ---------------------------------------------------------------------------
// Fused prep: one thread per (lb, n) item computes
//   psi(n) -> wsA, phi(n) -> wsB, torsion(n) -> wave-reduced tors_part[bid]
// Factorization: ||W u_j + k||^2 + eps = psi(i) . phi(j), where
// W = [Rp^T | -Rt^T] (3x6), k = -W u_i, Q = W^T W.
// psi: [0..5]=Q_cc, [6..20]=2Q_cd (c<d), [21..26]=2(W^T k)_c,
//      [27]=|k|^2+eps, [28]=bf16 residual of [27] (pairs with phi[28]=1)
// phi: [0..5]=u_c^2, [6..20]=u_c u_d, [21..26]=u_c, [27]=1, [28]=1
// ---------------------------------------------------------------------------
__global__ __launch_bounds__(PREP_THREADS)
void fused_prep_kernel(const float* __restrict__ traj_rot,    // [L,B,N,3,3]
                       const float* __restrict__ traj_trans,  // [L,B,N,3]
                       const float* __restrict__ traj_tors,   // [L,B,N,7,2]
                       const float* __restrict__ true_rot,    // [B,N,3,3]
                       const float* __restrict__ true_trans,  // [B,N,3]
                       const float* __restrict__ t_true,      // [B,N,7,2]
                       const float* __restrict__ t_alt,       // [B,N,7,2]
                       unsigned short* __restrict__ wsA,      // [ITEMS,32] bf16
                       unsigned short* __restrict__ wsB,      // [ITEMS,32] bf16
                       float* __restrict__ tors_part)         // [PREP_BLOCKS]
{
    const int g = blockIdx.x * PREP_THREADS + threadIdx.x;    // lb*N + n
    const int n  = g & (N - 1);
    const int lb = g >> 11;
    const int b  = lb & (B - 1);
    const int bn = b * N + n;

    // ---- psi ----
    const float* Rp = traj_rot + (size_t)g * 9;
    const float* Rt = true_rot + (size_t)bn * 9;
    const float* tp = traj_trans + (size_t)g * 3;
    const float* tt = true_trans + (size_t)bn * 3;

    float W0[6], W1[6], W2[6];
    #pragma unroll
    for (int c = 0; c < 3; ++c) {
        W0[c] = Rp[3 * c];      W1[c] = Rp[3 * c + 1];      W2[c] = Rp[3 * c + 2];
        W0[c + 3] = -Rt[3 * c]; W1[c + 3] = -Rt[3 * c + 1]; W2[c + 3] = -Rt[3 * c + 2];
    }
    float u[6] = { tp[0], tp[1], tp[2], tt[0], tt[1], tt[2] };

    float k0 = 0.f, k1 = 0.f, k2 = 0.f;
    #pragma unroll
    for (int c = 0; c < 6; ++c) {
        k0 = fmaf(W0[c], u[c], k0);
        k1 = fmaf(W1[c], u[c], k1);
        k2 = fmaf(W2[c], u[c], k2);
    }
    k0 = -k0; k1 = -k1; k2 = -k2;

    float psi[KF];
    #pragma unroll
    for (int c = 0; c < 6; ++c)
        psi[c] = fmaf(W0[c], W0[c], fmaf(W1[c], W1[c], W2[c] * W2[c]));
    int idx = 6;
    #pragma unroll
    for (int c = 0; c < 6; ++c)
        #pragma unroll
        for (int d = c + 1; d < 6; ++d)
            psi[idx++] = 2.0f * fmaf(W0[c], W0[d], fmaf(W1[c], W1[d], W2[c] * W2[d]));
    #pragma unroll
    for (int c = 0; c < 6; ++c)
        psi[21 + c] = 2.0f * fmaf(W0[c], k0, fmaf(W1[c], k1, W2[c] * k2));
    psi[27] = fmaf(k0, k0, fmaf(k1, k1, fmaf(k2, k2, FAPE_EPS)));
    psi[28] = psi[27] - bf2f(f2bf(psi[27]));   // residual channel
    psi[29] = psi[30] = psi[31] = 0.0f;

    unsigned short* outA = wsA + (size_t)g * KF;
    #pragma unroll
    for (int c = 0; c < KF; ++c) outA[c] = f2bf(psi[c]);

    // ---- phi ----
    float phi[KF];
    #pragma unroll
    for (int c = 0; c < 6; ++c) phi[c] = u[c] * u[c];
    idx = 6;
    #pragma unroll
    for (int c = 0; c < 6; ++c)
        #pragma unroll
        for (int d = c + 1; d < 6; ++d)
            phi[idx++] = u[c] * u[d];
    #pragma unroll
    for (int c = 0; c < 6; ++c) phi[21 + c] = u[c];
    phi[27] = 1.0f;
    phi[28] = 1.0f;
    phi[29] = phi[30] = phi[31] = 0.0f;

    unsigned short* outB = wsB + (size_t)g * KF;
    #pragma unroll
    for (int c = 0; c < KF; ++c) outB[c] = f2bf(phi[c]);

    // ---- torsion ----
    const float* p  = traj_tors + (size_t)g * 14;
    const float* tr = t_true + (size_t)bn * 14;
    const float* al = t_alt  + (size_t)bn * 14;

    float st = 0.0f, sa = 0.0f;
    #pragma unroll
    for (int k = 0; k < 7; ++k) {
        const float px = p[2 * k], py = p[2 * k + 1];
        const float nrm = fast_sqrtf(fmaf(px, px, fmaf(py, py, TEPS)));
        const float inv = __builtin_amdgcn_rcpf(nrm);
        const float pnx = px * inv, pny = py * inv;

        const float tx = tr[2 * k] - pnx, ty = tr[2 * k + 1] - pny;
        const float ax = al[2 * k] - pnx, ay = al[2 * k + 1] - pny;
        const float dt = fast_sqrtf(fmaf(tx, tx, fmaf(ty, ty, TEPS)));
        const float da = fast_sqrtf(fmaf(ax, ax, fmaf(ay, ay, TEPS)));

        st += fminf(dt, da);
        sa += fabsf(nrm - 1.0f);
    }
    const float val = (st + 0.02f * sa) * (1.0f / 7.0f);

    const float tot = wave_reduce_sum(val);     // one wave per block
    if (threadIdx.x == 0) tors_part[blockIdx.x] = tot;
}

// ---------------------------------------------------------------------------
// Fused FAPE + finalize: s_ij = psi(i).phi(j) via mfma_f32_16x16x32_bf16;
// epilogue acc += sqrt(med3(s,0,100)). Block: 64 i x 1024 j, 4 waves.
// Last block to finish (device-scope atomic counter) reduces all partials
// in a fixed order and writes out[0..1]. Tile-sum is lane-layout invariant.
// ---------------------------------------------------------------------------
__global__ __launch_bounds__(THREADS)
void fape_mfma_kernel(const unsigned short* __restrict__ wsA,
                      const unsigned short* __restrict__ wsB,
                      const float* __restrict__ tors_part,  // [PREP_BLOCKS]
                      float* __restrict__ fape_part,        // [FAPE_BLOCKS]
                      unsigned* __restrict__ counter,       // zeroed per call
                      float* __restrict__ out)              // [B]
{
    const int bid = blockIdx.x;
    const int jh  = bid & (JSPLIT - 1);
    const int it  = (bid >> 1) & (NIT - 1);
    const int lb  = bid >> 6;

    const int w    = threadIdx.x >> 6;
    const int lane = threadIdx.x & 63;
    const int wm   = w >> 1;          // i half (32 rows)
    const int wn   = w & 1;           // j quarter of 128-chunk (64 cols)
    const int r15  = lane & 15;
    const int koff = (lane >> 4) * 8;

    const size_t arow = (size_t)lb * N + (size_t)it * 64 + wm * 32 + r15;
    const bf16x8 a0 = *(const bf16x8*)(wsA + arow * KF + koff);
    const bf16x8 a1 = *(const bf16x8*)(wsA + (arow + 16) * KF + koff);

    const size_t brow0 = (size_t)lb * N + (size_t)jh * JHALF + wn * 64 + r15;
    const unsigned short* bp = wsB + brow0 * KF + koff;

    const f32x4 z = { 0.f, 0.f, 0.f, 0.f };
    float acc0 = 0.f, acc1 = 0.f, acc2 = 0.f, acc3 = 0.f;

    bf16x8 b0 = *(const bf16x8*)(bp);
    bf16x8 b1 = *(const bf16x8*)(bp + 16 * KF);
    bf16x8 b2 = *(const bf16x8*)(bp + 32 * KF);
    bf16x8 b3 = *(const bf16x8*)(bp + 48 * KF);

    #pragma unroll 1
    for (int jp = 0; jp < NPASS; ++jp) {
        const bf16x8 c0 = b0, c1 = b1, c2 = b2, c3 = b3;
        if (jp + 1 < NPASS) {          // prefetch next pass (hides L2 latency)
            bp += 128 * KF;
            b0 = *(const bf16x8*)(bp);
            b1 = *(const bf16x8*)(bp + 16 * KF);
            b2 = *(const bf16x8*)(bp + 32 * KF);
            b3 = *(const bf16x8*)(bp + 48 * KF);
        }

        f32x4 d0 = __builtin_amdgcn_mfma_f32_16x16x32_bf16(a0, c0, z, 0, 0, 0);
        f32x4 d1 = __builtin_amdgcn_mfma_f32_16x16x32_bf16(a0, c1, z, 0, 0, 0);
        f32x4 d2 = __builtin_amdgcn_mfma_f32_16x16x32_bf16(a0, c2, z, 0, 0, 0);
        f32x4 d3 = __builtin_amdgcn_mfma_f32_16x16x32_bf16(a0, c3, z, 0, 0, 0);
        f32x4 d4 = __builtin_amdgcn_mfma_f32_16x16x32_bf16(a1, c0, z, 0, 0, 0);
        f32x4 d5 = __builtin_amdgcn_mfma_f32_16x16x32_bf16(a1, c1, z, 0, 0, 0);
        f32x4 d6 = __builtin_amdgcn_mfma_f32_16x16x32_bf16(a1, c2, z, 0, 0, 0);
        f32x4 d7 = __builtin_amdgcn_mfma_f32_16x16x32_bf16(a1, c3, z, 0, 0, 0);

        // clamp(s,0,100) in one v_med3_f32; 4 accumulators break the add chain
        #pragma unroll
        for (int e = 0; e < 4; ++e) {
            acc0 += fast_sqrtf(__builtin_amdgcn_fmed3f(d0[e], 0.f, D_CLAMP2));
            acc1 += fast_sqrtf(__builtin_amdgcn_fmed3f(d1[e], 0.f, D_CLAMP2));
            acc2 += fast_sqrtf(__builtin_amdgcn_fmed3f(d2[e], 0.f, D_CLAMP2));
            acc3 += fast_sqrtf(__builtin_amdgcn_fmed3f(d3[e], 0.f, D_CLAMP2));
            acc0 += fast_sqrtf(__builtin_amdgcn_fmed3f(d4[e], 0.f, D_CLAMP2));
            acc1 += fast_sqrtf(__builtin_amdgcn_fmed3f(d5[e], 0.f, D_CLAMP2));
            acc2 += fast_sqrtf(__builtin_amdgcn_fmed3f(d6[e], 0.f, D_CLAMP2));
            acc3 += fast_sqrtf(__builtin_amdgcn_fmed3f(d7[e], 0.f, D_CLAMP2));
        }
    }

    const float tot = block_reduce_sum((acc0 + acc1) + (acc2 + acc3));

    __shared__ bool amLast;
    if (threadIdx.x == 0) {
        fape_part[bid] = tot;
        __threadfence();                          // publish partial (device scope)
        const unsigned prev = atomicAdd(counter, 1u);
        amLast = (prev == (unsigned)(FAPE_BLOCKS - 1));
    }
    __syncthreads();
    if (!amLast) return;
    __threadfence();                              // acquire all partials

    // ---- finalize (single block, fixed order -> deterministic) ----
    float fs0 = 0.0f, fs1 = 0.0f;
    for (int t = threadIdx.x; t < FAPE_BLOCKS; t += THREADS) {
        const float v = fape_part[t];
        if ((t >> 6) & 1) fs1 += v; else fs0 += v;    // lb = t>>6, parity = b
    }
    float ts0 = 0.0f, ts1 = 0.0f;
    for (int t = threadIdx.x; t < PREP_BLOCKS; t += THREADS) {
        const float v = tors_part[t];
        if ((t >> 5) & 1) ts1 += v; else ts0 += v;    // lb = t>>5 (32 blocks/lb)
    }
    const float F0 = block_reduce_sum(fs0);
    const float F1 = block_reduce_sum(fs1);
    const float T0 = block_reduce_sum(ts0);
    const float T1 = block_reduce_sum(ts1);
    if (threadIdx.x == 0) {
        const float inv_pairs = 1.0f / ((float)N * (float)N * Z_CONST);
        out[0] = (F0 * inv_pairs + T0 / (float)N) / (float)L;
        out[1] = (F1 * inv_pairs + T1 / (float)N) / (float)L;
    }
}

extern "C" void kernel_launch(void* const* d_in, const int* in_sizes, int n_in,
                              void* d_out, int out_size, void* d_ws, size_t ws_size,
                              hipStream_t stream)
{
    const float* traj_rot   = (const float*)d_in[0];
    const float* traj_trans = (const float*)d_in[1];
    const float* traj_tors  = (const float*)d_in[2];
    const float* true_rot   = (const float*)d_in[3];
    const float* true_trans = (const float*)d_in[4];
    const float* true_ta    = (const float*)d_in[5];
    const float* true_taa   = (const float*)d_in[6];

    float* out = (float*)d_out;

    unsigned short* wsA = (unsigned short*)d_ws;          // ITEMS*32 bf16 = 2 MB
    unsigned short* wsB = wsA + (size_t)ITEMS * KF;       // 2 MB
    float*    fape_part = (float*)(wsB + (size_t)ITEMS * KF);   // 1024 f
    float*    tors_part = fape_part + FAPE_BLOCKS;              // 512 f
    unsigned* counter   = (unsigned*)(tors_part + PREP_BLOCKS); // 1 u32

    // counter must be 0 at every call (graph replays it as a memset node)
    hipMemsetAsync(counter, 0, sizeof(unsigned), stream);

    fused_prep_kernel<<<PREP_BLOCKS, PREP_THREADS, 0, stream>>>(
        traj_rot, traj_trans, traj_tors, true_rot, true_trans,
        true_ta, true_taa, wsA, wsB, tors_part);
    fape_mfma_kernel<<<FAPE_BLOCKS, THREADS, 0, stream>>>(
        wsA, wsB, tors_part, fape_part, counter, out);
}

// Round 7
// 23.705 us; speedup vs baseline: 2.0968x; 2.0968x over previous
//
#include <hip/hip_runtime.h>
#include <math.h>

// Problem constants (setup_inputs: L=8, B=2, N=2048)
constexpr int L = 8;
constexpr int B = 2;
constexpr int N = 2048;
constexpr int LB = L * B;            // 16
constexpr int ITEMS = LB * N;        // 32768
constexpr int KF = 32;               // padded feature dim (28 used + residual)

constexpr float D_CLAMP2 = 100.0f;   // clamp on squared distance
constexpr float FAPE_EPS = 1e-4f;
constexpr float Z_CONST  = 10.0f;
constexpr float TEPS     = 1e-8f;

constexpr int THREADS = 256;
constexpr int JSPLIT  = 4;                   // j split per (l,b)
constexpr int JCH     = N / JSPLIT;          // 512 j per block
constexpr int NPASS   = JCH / 128;           // 4
constexpr int NIT     = N / 64;              // 32 i-tiles per (l,b)
constexpr int FAPE_BLOCKS = LB * NIT * JSPLIT;   // 2048 (128 blocks per lb)
constexpr int TORS_PER_BLK = ITEMS / FAPE_BLOCKS; // 16 torsion items per block

typedef __attribute__((ext_vector_type(8))) short bf16x8;
typedef __attribute__((ext_vector_type(4))) float f32x4;

__device__ __forceinline__ float fast_sqrtf(float x) {
    return __builtin_amdgcn_sqrtf(x);
}
__device__ __forceinline__ unsigned short f2bf(float x) {  // RNE f32->bf16
    unsigned u = __float_as_uint(x);
    u += 0x7fffu + ((u >> 16) & 1u);
    return (unsigned short)(u >> 16);
}
__device__ __forceinline__ float bf2f(unsigned short h) {
    return __uint_as_float((unsigned)h << 16);
}

__device__ __forceinline__ float wave_reduce_sum(float v) {
    #pragma unroll
    for (int off = 32; off > 0; off >>= 1)
        v += __shfl_down(v, off, 64);
    return v;            // valid in lane 0
}

__device__ __forceinline__ float block_reduce_sum(float v) {
    __shared__ float s[4];
    v = wave_reduce_sum(v);
    int lane = threadIdx.x & 63;
    int w    = threadIdx.x >> 6;
    __syncthreads();
    if (lane == 0) s[w] = v;
    __syncthreads();
    return s[0] + s[1] + s[2] + s[3];   // fixed order -> deterministic
}

// LDS chunk swizzle: 16B chunk c of row r stored at position c ^ ((r>>1)&3).
// Read pattern (16 consecutive rows x 4 k-chunks) then spreads 64 lanes
// evenly over all 32 banks (2 lanes/bank-group = structural minimum).
__device__ __forceinline__ void store_row(short* base, int r, const float* f) {
    #pragma unroll
    for (int c = 0; c < 4; ++c) {
        bf16x8 v;
        #pragma unroll
        for (int e = 0; e < 8; ++e) v[e] = (short)f2bf(f[8 * c + e]);
        const int p = c ^ ((r >> 1) & 3);
        *(bf16x8*)(base + r * KF + p * 8) = v;
    }
}
__device__ __forceinline__ bf16x8 load_frag(const short* base, int r, int c) {
    const int p = c ^ ((r >> 1) & 3);
    return *(const bf16x8*)(base + r * KF + p * 8);
}

// ---------------------------------------------------------------------------
// Self-sufficient FAPE block: computes its own psi (64 i-rows) and phi
// (512 j-rows) features into LDS, its torsion slice (16 items), then the
// MFMA pair loop.  partial[bid] = fape_sum/(N*N*Z) + tors_sum/N.
// Factorization: ||W u_j + k||^2 + eps = psi(i) . phi(j), W=[Rp^T|-Rt^T],
// k = -W u_i.  psi: [0..5]=Q_cc, [6..20]=2Q_cd, [21..26]=2(W^T k)_c,
// [27]=|k|^2+eps, [28]=bf16 residual of [27]; phi: [u_c^2, u_c u_d, u_c, 1, 1].
// ---------------------------------------------------------------------------
__global__ __launch_bounds__(THREADS)
void fape_all_kernel(const float* __restrict__ traj_rot,    // [L,B,N,3,3]
                     const float* __restrict__ traj_trans,  // [L,B,N,3]
                     const float* __restrict__ traj_tors,   // [L,B,N,7,2]
                     const float* __restrict__ true_rot,    // [B,N,3,3]
                     const float* __restrict__ true_trans,  // [B,N,3]
                     const float* __restrict__ t_true,      // [B,N,7,2]
                     const float* __restrict__ t_alt,       // [B,N,7,2]
                     float* __restrict__ partials)          // [FAPE_BLOCKS]
{
    __shared__ short phiL[JCH * KF];   // 32 KB
    __shared__ short psiL[64 * KF];    // 4 KB
    __shared__ float tors_s;

    const int bid = blockIdx.x;
    const int jh  = bid & (JSPLIT - 1);
    const int it  = (bid >> 2) & (NIT - 1);
    const int lb  = bid >> 7;            // 128 blocks per lb
    const int b   = lb & (B - 1);
    const int tid = threadIdx.x;

    const float* tp = traj_trans + (size_t)lb * N * 3;
    const float* tt = true_trans + (size_t)b  * N * 3;

    // ---- phi prep: rows tid and tid+256 ----
    #pragma unroll
    for (int half = 0; half < 2; ++half) {
        const int r = tid + half * THREADS;      // 0..511
        const int j = jh * JCH + r;
        float u[6] = { tp[3 * j], tp[3 * j + 1], tp[3 * j + 2],
                       tt[3 * j], tt[3 * j + 1], tt[3 * j + 2] };
        float phi[KF];
        #pragma unroll
        for (int c = 0; c < 6; ++c) phi[c] = u[c] * u[c];
        int idx = 6;
        #pragma unroll
        for (int c = 0; c < 6; ++c)
            #pragma unroll
            for (int d = c + 1; d < 6; ++d)
                phi[idx++] = u[c] * u[d];
        #pragma unroll
        for (int c = 0; c < 6; ++c) phi[21 + c] = u[c];
        phi[27] = 1.0f;
        phi[28] = 1.0f;
        phi[29] = phi[30] = phi[31] = 0.0f;
        store_row(phiL, r, phi);
    }

    if (tid < 64) {
        // ---- psi prep: wave 0, one i-row per lane ----
        const int r = tid;
        const int i = it * 64 + r;
        const float* Rp = traj_rot + ((size_t)lb * N + i) * 9;
        const float* Rt = true_rot + ((size_t)(b * N + i)) * 9;

        float W0[6], W1[6], W2[6];
        #pragma unroll
        for (int c = 0; c < 3; ++c) {
            W0[c] = Rp[3 * c];      W1[c] = Rp[3 * c + 1];      W2[c] = Rp[3 * c + 2];
            W0[c + 3] = -Rt[3 * c]; W1[c + 3] = -Rt[3 * c + 1]; W2[c + 3] = -Rt[3 * c + 2];
        }
        float u[6] = { tp[3 * i], tp[3 * i + 1], tp[3 * i + 2],
                       tt[3 * i], tt[3 * i + 1], tt[3 * i + 2] };

        float k0 = 0.f, k1 = 0.f, k2 = 0.f;
        #pragma unroll
        for (int c = 0; c < 6; ++c) {
            k0 = fmaf(W0[c], u[c], k0);
            k1 = fmaf(W1[c], u[c], k1);
            k2 = fmaf(W2[c], u[c], k2);
        }
        k0 = -k0; k1 = -k1; k2 = -k2;

        float psi[KF];
        #pragma unroll
        for (int c = 0; c < 6; ++c)
            psi[c] = fmaf(W0[c], W0[c], fmaf(W1[c], W1[c], W2[c] * W2[c]));
        int idx = 6;
        #pragma unroll
        for (int c = 0; c < 6; ++c)
            #pragma unroll
            for (int d = c + 1; d < 6; ++d)
                psi[idx++] = 2.0f * fmaf(W0[c], W0[d], fmaf(W1[c], W1[d], W2[c] * W2[d]));
        #pragma unroll
        for (int c = 0; c < 6; ++c)
            psi[21 + c] = 2.0f * fmaf(W0[c], k0, fmaf(W1[c], k1, W2[c] * k2));
        psi[27] = fmaf(k0, k0, fmaf(k1, k1, fmaf(k2, k2, FAPE_EPS)));
        psi[28] = psi[27] - bf2f(f2bf(psi[27]));   // residual channel
        psi[29] = psi[30] = psi[31] = 0.0f;
        store_row(psiL, r, psi);
    } else if (tid < 128) {
        // ---- torsion: wave 1 (16 active lanes, rest contribute 0) ----
        const int t = tid - 64;
        float val = 0.0f;
        if (t < TORS_PER_BLK) {
            const int g  = bid * TORS_PER_BLK + t;       // lb*N + n (same lb)
            const int n  = g & (N - 1);
            const int bn = b * N + n;
            const float* p  = traj_tors + (size_t)g * 14;
            const float* tr = t_true + (size_t)bn * 14;
            const float* al = t_alt  + (size_t)bn * 14;

            float st = 0.0f, sa = 0.0f;
            #pragma unroll
            for (int k = 0; k < 7; ++k) {
                const float px = p[2 * k], py = p[2 * k + 1];
                const float nrm = fast_sqrtf(fmaf(px, px, fmaf(py, py, TEPS)));
                const float inv = __builtin_amdgcn_rcpf(nrm);
                const float pnx = px * inv, pny = py * inv;
                const float tx = tr[2 * k] - pnx, ty = tr[2 * k + 1] - pny;
                const float ax = al[2 * k] - pnx, ay = al[2 * k + 1] - pny;
                const float dt = fast_sqrtf(fmaf(tx, tx, fmaf(ty, ty, TEPS)));
                const float da = fast_sqrtf(fmaf(ax, ax, fmaf(ay, ay, TEPS)));
                st += fminf(dt, da);
                sa += fabsf(nrm - 1.0f);
            }
            val = (st + 0.02f * sa) * (1.0f / 7.0f);
        }
        val = wave_reduce_sum(val);
        if (tid == 64) tors_s = val;
    }

    __syncthreads();

    // ---- MFMA pair loop: 64 i x 512 j, 4 waves (wm x wn), 4 passes ----
    const int w    = tid >> 6;
    const int lane = tid & 63;
    const int wm   = w >> 1;
    const int wn   = w & 1;
    const int r15  = lane & 15;
    const int cch  = lane >> 4;          // k-chunk 0..3

    const bf16x8 a0 = load_frag(psiL, wm * 32 + r15, cch);
    const bf16x8 a1 = load_frag(psiL, wm * 32 + 16 + r15, cch);

    const f32x4 z = { 0.f, 0.f, 0.f, 0.f };
    float acc0 = 0.f, acc1 = 0.f, acc2 = 0.f, acc3 = 0.f;

    #pragma unroll
    for (int jp = 0; jp < NPASS; ++jp) {
        const int rb = jp * 128 + wn * 64 + r15;
        const bf16x8 b0 = load_frag(phiL, rb,      cch);
        const bf16x8 b1 = load_frag(phiL, rb + 16, cch);
        const bf16x8 b2 = load_frag(phiL, rb + 32, cch);
        const bf16x8 b3 = load_frag(phiL, rb + 48, cch);

        f32x4 d0 = __builtin_amdgcn_mfma_f32_16x16x32_bf16(a0, b0, z, 0, 0, 0);
        f32x4 d1 = __builtin_amdgcn_mfma_f32_16x16x32_bf16(a0, b1, z, 0, 0, 0);
        f32x4 d2 = __builtin_amdgcn_mfma_f32_16x16x32_bf16(a0, b2, z, 0, 0, 0);
        f32x4 d3 = __builtin_amdgcn_mfma_f32_16x16x32_bf16(a0, b3, z, 0, 0, 0);
        f32x4 d4 = __builtin_amdgcn_mfma_f32_16x16x32_bf16(a1, b0, z, 0, 0, 0);
        f32x4 d5 = __builtin_amdgcn_mfma_f32_16x16x32_bf16(a1, b1, z, 0, 0, 0);
        f32x4 d6 = __builtin_amdgcn_mfma_f32_16x16x32_bf16(a1, b2, z, 0, 0, 0);
        f32x4 d7 = __builtin_amdgcn_mfma_f32_16x16x32_bf16(a1, b3, z, 0, 0, 0);

        #pragma unroll
        for (int e = 0; e < 4; ++e) {
            acc0 += fast_sqrtf(__builtin_amdgcn_fmed3f(d0[e], 0.f, D_CLAMP2));
            acc1 += fast_sqrtf(__builtin_amdgcn_fmed3f(d1[e], 0.f, D_CLAMP2));
            acc2 += fast_sqrtf(__builtin_amdgcn_fmed3f(d2[e], 0.f, D_CLAMP2));
            acc3 += fast_sqrtf(__builtin_amdgcn_fmed3f(d3[e], 0.f, D_CLAMP2));
            acc0 += fast_sqrtf(__builtin_amdgcn_fmed3f(d4[e], 0.f, D_CLAMP2));
            acc1 += fast_sqrtf(__builtin_amdgcn_fmed3f(d5[e], 0.f, D_CLAMP2));
            acc2 += fast_sqrtf(__builtin_amdgcn_fmed3f(d6[e], 0.f, D_CLAMP2));
            acc3 += fast_sqrtf(__builtin_amdgcn_fmed3f(d7[e], 0.f, D_CLAMP2));
        }
    }

    const float tot = block_reduce_sum((acc0 + acc1) + (acc2 + acc3));
    if (tid == 0) {
        const float inv_pairs = 1.0f / ((float)N * (float)N * Z_CONST);
        partials[bid] = tot * inv_pairs + tors_s * (1.0f / (float)N);
    }
}

// ---------------------------------------------------------------------------
// Finalize: out[b] = (1/L) * sum over partials of that b (lb = t>>7)
// ---------------------------------------------------------------------------
__global__ __launch_bounds__(THREADS)
void finalize_kernel(const float* __restrict__ partials,
                     float* __restrict__ out)
{
    float fs0 = 0.0f, fs1 = 0.0f;
    for (int t = threadIdx.x; t < FAPE_BLOCKS; t += THREADS) {
        const float v = partials[t];
        if ((t >> 7) & 1) fs1 += v; else fs0 += v;
    }
    const float F0 = block_reduce_sum(fs0);
    const float F1 = block_reduce_sum(fs1);
    if (threadIdx.x == 0) {
        out[0] = F0 / (float)L;
        out[1] = F1 / (float)L;
    }
}

extern "C" void kernel_launch(void* const* d_in, const int* in_sizes, int n_in,
                              void* d_out, int out_size, void* d_ws, size_t ws_size,
                              hipStream_t stream)
{
    const float* traj_rot   = (const float*)d_in[0];
    const float* traj_trans = (const float*)d_in[1];
    const float* traj_tors  = (const float*)d_in[2];
    const float* true_rot   = (const float*)d_in[3];
    const float* true_trans = (const float*)d_in[4];
    const float* true_ta    = (const float*)d_in[5];
    const float* true_taa   = (const float*)d_in[6];

    float* out      = (float*)d_out;
    float* partials = (float*)d_ws;                  // FAPE_BLOCKS floats

    fape_all_kernel<<<FAPE_BLOCKS, THREADS, 0, stream>>>(
        traj_rot, traj_trans, traj_tors, true_rot, true_trans,
        true_ta, true_taa, partials);
    finalize_kernel<<<1, THREADS, 0, stream>>>(partials, out);
}

// Round 8
// 20.614 us; speedup vs baseline: 2.4111x; 1.1499x over previous
//
#include <hip/hip_runtime.h>
#include <math.h>

// Problem constants (setup_inputs: L=8, B=2, N=2048)
constexpr int L = 8;
constexpr int B = 2;
constexpr int N = 2048;
constexpr int LB = L * B;            // 16
constexpr int KF = 32;               // padded feature dim (28 used + residual)

constexpr float D_CLAMP2 = 100.0f;   // clamp on squared distance
constexpr float FAPE_EPS = 1e-4f;
constexpr float Z_CONST  = 10.0f;
constexpr float TEPS     = 1e-8f;

constexpr int THREADS = 256;
constexpr int IBLK    = 256;                 // i rows per block
constexpr int JCH     = 512;                 // j cols per block
constexpr int NIT     = N / IBLK;            // 8 i-tiles per (l,b)
constexpr int JSPLIT  = N / JCH;             // 4 j-chunks per (l,b)
constexpr int BLK_PER_LB  = NIT * JSPLIT;    // 32
constexpr int FAPE_BLOCKS = LB * BLK_PER_LB; // 512 (2 per CU, 1 round)
constexpr int TORS_PER_BLK = N / BLK_PER_LB; // 64 torsion items per block

typedef __attribute__((ext_vector_type(8))) short bf16x8;
typedef __attribute__((ext_vector_type(4))) float f32x4;

__device__ __forceinline__ float fast_sqrtf(float x) {
    return __builtin_amdgcn_sqrtf(x);
}
// HW packed f32->bf16 (RNE on gfx950); 1 instr per 2 values
__device__ __forceinline__ unsigned cvt_pk(float lo, float hi) {
    unsigned r;
    asm("v_cvt_pk_bf16_f32 %0, %1, %2" : "=v"(r) : "v"(lo), "v"(hi));
    return r;
}
__device__ __forceinline__ float bf2f(unsigned short h) {
    return __uint_as_float((unsigned)h << 16);
}

__device__ __forceinline__ float wave_reduce_sum(float v) {
    #pragma unroll
    for (int off = 32; off > 0; off >>= 1)
        v += __shfl_down(v, off, 64);
    return v;            // valid in lane 0
}

__device__ __forceinline__ float block_reduce_sum(float v) {
    __shared__ float s[4];
    v = wave_reduce_sum(v);
    int lane = threadIdx.x & 63;
    int w    = threadIdx.x >> 6;
    __syncthreads();
    if (lane == 0) s[w] = v;
    __syncthreads();
    return s[0] + s[1] + s[2] + s[3];   // fixed order -> deterministic
}

// LDS chunk swizzle: 16B chunk c of row r stored at position c ^ ((r>>1)&3).
// Both the write (64 lanes x 4 chunks) and the MFMA-fragment read
// (16 rows x 4 k-chunks) then hit each bank exactly twice per wave access
// = structural minimum (verified 0 SQ_LDS_BANK_CONFLICT in round 7).
__device__ __forceinline__ void store_row(short* base, int r, const float* f) {
    #pragma unroll
    for (int c = 0; c < 4; ++c) {
        union { unsigned u[4]; bf16x8 v; } q;
        #pragma unroll
        for (int e = 0; e < 4; ++e)
            q.u[e] = cvt_pk(f[8 * c + 2 * e], f[8 * c + 2 * e + 1]);
        const int p = c ^ ((r >> 1) & 3);
        *(bf16x8*)(base + r * KF + p * 8) = q.v;
    }
}
__device__ __forceinline__ bf16x8 load_frag(const short* base, int r, int c) {
    const int p = c ^ ((r >> 1) & 3);
    return *(const bf16x8*)(base + r * KF + p * 8);
}

// ---------------------------------------------------------------------------
// Self-sufficient FAPE block: 256 i x 512 j. Computes its psi (256 rows) and
// phi (512 rows) features into LDS, its torsion slice (64 items), then the
// MFMA pair loop. partial[bid] = fape_sum/(N*N*Z) + tors_sum/N.
// Factorization: ||W u_j + k||^2 + eps = psi(i) . phi(j), W=[Rp^T|-Rt^T],
// k = -W u_i.  psi: [0..5]=Q_cc, [6..20]=2Q_cd, [21..26]=2(W^T k)_c,
// [27]=|k|^2+eps, [28]=bf16 residual of [27]; phi: [u_c^2, u_c u_d, u_c, 1, 1].
// ---------------------------------------------------------------------------
__global__ __launch_bounds__(THREADS)
void fape_all_kernel(const float* __restrict__ traj_rot,    // [L,B,N,3,3]
                     const float* __restrict__ traj_trans,  // [L,B,N,3]
                     const float* __restrict__ traj_tors,   // [L,B,N,7,2]
                     const float* __restrict__ true_rot,    // [B,N,3,3]
                     const float* __restrict__ true_trans,  // [B,N,3]
                     const float* __restrict__ t_true,      // [B,N,7,2]
                     const float* __restrict__ t_alt,       // [B,N,7,2]
                     float* __restrict__ partials)          // [FAPE_BLOCKS]
{
    __shared__ short phiL[JCH * KF];    // 32 KB
    __shared__ short psiL[IBLK * KF];   // 16 KB
    __shared__ float tors_s;

    const int bid = blockIdx.x;
    const int jh  = bid & (JSPLIT - 1);
    const int it  = (bid >> 2) & (NIT - 1);
    const int lb  = bid >> 5;            // 32 blocks per lb
    const int b   = lb & (B - 1);
    const int tid = threadIdx.x;

    const float* tp = traj_trans + (size_t)lb * N * 3;
    const float* tt = true_trans + (size_t)b  * N * 3;

    // ---- phi prep: rows tid and tid+256 ----
    #pragma unroll
    for (int half = 0; half < 2; ++half) {
        const int r = tid + half * THREADS;      // 0..511
        const int j = jh * JCH + r;
        float u[6] = { tp[3 * j], tp[3 * j + 1], tp[3 * j + 2],
                       tt[3 * j], tt[3 * j + 1], tt[3 * j + 2] };
        float phi[KF];
        #pragma unroll
        for (int c = 0; c < 6; ++c) phi[c] = u[c] * u[c];
        int idx = 6;
        #pragma unroll
        for (int c = 0; c < 6; ++c)
            #pragma unroll
            for (int d = c + 1; d < 6; ++d)
                phi[idx++] = u[c] * u[d];
        #pragma unroll
        for (int c = 0; c < 6; ++c) phi[21 + c] = u[c];
        phi[27] = 1.0f;
        phi[28] = 1.0f;
        phi[29] = phi[30] = phi[31] = 0.0f;
        store_row(phiL, r, phi);
    }

    // ---- psi prep: one i-row per thread ----
    {
        const int r = tid;
        const int i = it * IBLK + r;
        const float* Rp = traj_rot + ((size_t)lb * N + i) * 9;
        const float* Rt = true_rot + ((size_t)(b * N + i)) * 9;

        float W0[6], W1[6], W2[6];
        #pragma unroll
        for (int c = 0; c < 3; ++c) {
            W0[c] = Rp[3 * c];      W1[c] = Rp[3 * c + 1];      W2[c] = Rp[3 * c + 2];
            W0[c + 3] = -Rt[3 * c]; W1[c + 3] = -Rt[3 * c + 1]; W2[c + 3] = -Rt[3 * c + 2];
        }
        float u[6] = { tp[3 * i], tp[3 * i + 1], tp[3 * i + 2],
                       tt[3 * i], tt[3 * i + 1], tt[3 * i + 2] };

        float k0 = 0.f, k1 = 0.f, k2 = 0.f;
        #pragma unroll
        for (int c = 0; c < 6; ++c) {
            k0 = fmaf(W0[c], u[c], k0);
            k1 = fmaf(W1[c], u[c], k1);
            k2 = fmaf(W2[c], u[c], k2);
        }
        k0 = -k0; k1 = -k1; k2 = -k2;

        float psi[KF];
        #pragma unroll
        for (int c = 0; c < 6; ++c)
            psi[c] = fmaf(W0[c], W0[c], fmaf(W1[c], W1[c], W2[c] * W2[c]));
        int idx = 6;
        #pragma unroll
        for (int c = 0; c < 6; ++c)
            #pragma unroll
            for (int d = c + 1; d < 6; ++d)
                psi[idx++] = 2.0f * fmaf(W0[c], W0[d], fmaf(W1[c], W1[d], W2[c] * W2[d]));
        #pragma unroll
        for (int c = 0; c < 6; ++c)
            psi[21 + c] = 2.0f * fmaf(W0[c], k0, fmaf(W1[c], k1, W2[c] * k2));
        psi[27] = fmaf(k0, k0, fmaf(k1, k1, fmaf(k2, k2, FAPE_EPS)));
        // residual vs the SAME hw conversion the store uses -> self-consistent
        psi[28] = psi[27] - bf2f((unsigned short)(cvt_pk(psi[27], psi[27]) & 0xffffu));
        psi[29] = psi[30] = psi[31] = 0.0f;
        store_row(psiL, r, psi);
    }

    // ---- torsion: wave 0, one item per lane (64 items per block) ----
    if (tid < 64) {
        const int g  = lb * N + (bid & 31) * TORS_PER_BLK + tid;   // lb*N + n
        const int n  = g & (N - 1);
        const int bn = b * N + n;
        const float* p  = traj_tors + (size_t)g * 14;
        const float* tr = t_true + (size_t)bn * 14;
        const float* al = t_alt  + (size_t)bn * 14;

        float st = 0.0f, sa = 0.0f;
        #pragma unroll
        for (int k = 0; k < 7; ++k) {
            const float px = p[2 * k], py = p[2 * k + 1];
            const float nrm = fast_sqrtf(fmaf(px, px, fmaf(py, py, TEPS)));
            const float inv = __builtin_amdgcn_rcpf(nrm);
            const float pnx = px * inv, pny = py * inv;
            const float tx = tr[2 * k] - pnx, ty = tr[2 * k + 1] - pny;
            const float ax = al[2 * k] - pnx, ay = al[2 * k + 1] - pny;
            const float dt = fast_sqrtf(fmaf(tx, tx, fmaf(ty, ty, TEPS)));
            const float da = fast_sqrtf(fmaf(ax, ax, fmaf(ay, ay, TEPS)));
            st += fminf(dt, da);
            sa += fabsf(nrm - 1.0f);
        }
        float val = (st + 0.02f * sa) * (1.0f / 7.0f);
        val = wave_reduce_sum(val);
        if (tid == 0) tors_s = val;
    }

    __syncthreads();

    // ---- MFMA pair loop: 4 waves, each 128 i x 256 j ----
    const int w    = tid >> 6;
    const int lane = tid & 63;
    const int wm   = w >> 1;             // i half (128 rows)
    const int wn   = w & 1;              // j half (256 cols)
    const int r15  = lane & 15;
    const int cch  = lane >> 4;          // k-chunk 0..3

    bf16x8 a[8];                         // 8 A-frags held in registers (32 VGPR)
    #pragma unroll
    for (int s = 0; s < 8; ++s)
        a[s] = load_frag(psiL, wm * 128 + s * 16 + r15, cch);

    const f32x4 z = { 0.f, 0.f, 0.f, 0.f };
    float acc0 = 0.f, acc1 = 0.f, acc2 = 0.f, acc3 = 0.f;

    #pragma unroll
    for (int jp = 0; jp < 4; ++jp) {             // 4 j-passes of 64
        const int rb = wn * 256 + jp * 64 + r15;
        #pragma unroll
        for (int q = 0; q < 4; ++q) {            // 4 B-frags per pass
            const bf16x8 bq = load_frag(phiL, rb + q * 16, cch);
            f32x4 d[8];
            #pragma unroll
            for (int s = 0; s < 8; ++s)
                d[s] = __builtin_amdgcn_mfma_f32_16x16x32_bf16(a[s], bq, z, 0, 0, 0);
            #pragma unroll
            for (int s = 0; s < 8; ++s) {
                acc0 += fast_sqrtf(__builtin_amdgcn_fmed3f(d[s][0], 0.f, D_CLAMP2));
                acc1 += fast_sqrtf(__builtin_amdgcn_fmed3f(d[s][1], 0.f, D_CLAMP2));
                acc2 += fast_sqrtf(__builtin_amdgcn_fmed3f(d[s][2], 0.f, D_CLAMP2));
                acc3 += fast_sqrtf(__builtin_amdgcn_fmed3f(d[s][3], 0.f, D_CLAMP2));
            }
        }
    }

    const float tot = block_reduce_sum((acc0 + acc1) + (acc2 + acc3));
    if (tid == 0) {
        const float inv_pairs = 1.0f / ((float)N * (float)N * Z_CONST);
        partials[bid] = tot * inv_pairs + tors_s * (1.0f / (float)N);
    }
}

// ---------------------------------------------------------------------------
// Finalize: out[b] = (1/L) * sum over partials of that b (lb = t>>5)
// ---------------------------------------------------------------------------
__global__ __launch_bounds__(THREADS)
void finalize_kernel(const float* __restrict__ partials,
                     float* __restrict__ out)
{
    float fs0 = 0.0f, fs1 = 0.0f;
    for (int t = threadIdx.x; t < FAPE_BLOCKS; t += THREADS) {
        const float v = partials[t];
        if ((t >> 5) & 1) fs1 += v; else fs0 += v;
    }
    const float F0 = block_reduce_sum(fs0);
    const float F1 = block_reduce_sum(fs1);
    if (threadIdx.x == 0) {
        out[0] = F0 / (float)L;
        out[1] = F1 / (float)L;
    }
}

extern "C" void kernel_launch(void* const* d_in, const int* in_sizes, int n_in,
                              void* d_out, int out_size, void* d_ws, size_t ws_size,
                              hipStream_t stream)
{
    const float* traj_rot   = (const float*)d_in[0];
    const float* traj_trans = (const float*)d_in[1];
    const float* traj_tors  = (const float*)d_in[2];
    const float* true_rot   = (const float*)d_in[3];
    const float* true_trans = (const float*)d_in[4];
    const float* true_ta    = (const float*)d_in[5];
    const float* true_taa   = (const float*)d_in[6];

    float* out      = (float*)d_out;
    float* partials = (float*)d_ws;                  // FAPE_BLOCKS floats

    fape_all_kernel<<<FAPE_BLOCKS, THREADS, 0, stream>>>(
        traj_rot, traj_trans, traj_tors, true_rot, true_trans,
        true_ta, true_taa, partials);
    finalize_kernel<<<1, THREADS, 0, stream>>>(partials, out);
}